// Round 4
// baseline (66.566 us; speedup 1.0000x reference)
//
#include <hip/hip_runtime.h>
#include <stdint.h>

#define IN_    128
#define OUT_   128
#define KK_    16
#define BPB    8          // batches per block
#define SSTR   9          // sbT byte stride per position (9 -> conflict-free stage-2 writes)
// grid = OUT_ * (128/BPB) = 2048 blocks, 256 threads, 8 blocks/CU (full occupancy)

__global__ __launch_bounds__(256, 8) void linlut_kernel(
    const float* __restrict__ x, const float* __restrict__ w,
    const float* __restrict__ bias, const float* __restrict__ means,
    const int* __restrict__ mask, float* __restrict__ out)
{
    __shared__ float         lut[128 * 33];          // lut[i*33 + lvl*16 + S]
    __shared__ unsigned char sbT[IN_ * SSTR];        // sbT[pos*9 + batch]: s0 | s1<<1
    __shared__ uint32_t      pidx[128];              // 4 gather indices per i, byte-packed
    __shared__ float         wpart[4][8];            // per-wave partials per batch

    const int tid = threadIdx.x;
    // XCD swizzle: the 16 batch-group blocks of one o land on one XCD (L2 reuse of w/mask)
    const uint32_t bid = blockIdx.x;
    const uint32_t L   = (bid & 7u) * 256u + (bid >> 3);   // bijective, 2048 % 8 == 0
    const int o  = (int)(L >> 4);
    const int b0 = (int)(L & 15u) * BPB;

    // ---- issue ALL global loads up front: cold misses overlap instead of serializing ----
    const int i3  = tid >> 1;                        // LUT row 0..127
    const int lvl = tid & 1;
    const float4* wr = (const float4*)(w + ((size_t)(o * IN_ + i3)) * KK_);
    const float4 w0 = wr[0], w1 = wr[1], w2 = wr[2], w3 = wr[3];

    const int xb = tid >> 5, xg = tid & 31;          // batch 0..7, pos-group 0..31
    const float4 xv = *(const float4*)(x + (size_t)(b0 + xb) * IN_ + xg * 4);

    int4 mm = make_int4(0, 0, 0, 0);
    if (tid < 128) mm = *(const int4*)(mask + ((size_t)(o * IN_ + tid)) * 4);

    const float m0 = fabsf(means[0]);
    const float m1 = fabsf(means[1]);
    const float bo = bias[o];

    // ---- stage 1: pack gather indices ----
    if (tid < 128)
        pidx[tid] = (uint32_t)mm.x | ((uint32_t)mm.y << 8) |
                    ((uint32_t)mm.z << 16) | ((uint32_t)mm.w << 24);

    // ---- stage 2: sign bytes for this block's 8 batches, transposed sbT[pos][b] ----
    {
        const float vv[4] = {xv.x, xv.y, xv.z, xv.w};
        #pragma unroll
        for (int k = 0; k < 4; ++k) {
            const uint32_t s0 = (vv[k] >= 0.0f) ? 1u : 0u;
            const float r = vv[k] - (s0 ? m0 : -m0);     // same f32 ops as reference
            const uint32_t s1 = (r >= 0.0f) ? 1u : 0u;
            sbT[(4 * xg + k) * SSTR + xb] = (unsigned char)(s0 | (s1 << 1));
        }
    }

    // ---- stage 3: LUT slice via Walsh-Hadamard: lut = H * diag(m^|t|/16) * H * w ----
    // (p+q = 1, p-q = m  =>  pw[popc(S^c)] = (1/16) * sum_t m^|t| (-1)^{(S^c).t})
    {
        const float m = lvl ? m1 : m0;
        float v[16] = {w0.x, w0.y, w0.z, w0.w, w1.x, w1.y, w1.z, w1.w,
                       w2.x, w2.y, w2.z, w2.w, w3.x, w3.y, w3.z, w3.w};
        #pragma unroll
        for (int s = 1; s < 16; s <<= 1)
            #pragma unroll
            for (int a = 0; a < 16; ++a)
                if ((a & s) == 0) {
                    const float u = v[a], t2 = v[a | s];
                    v[a] = u + t2; v[a | s] = u - t2;
                }
        const float c0 = 0.0625f;
        const float c1 = m * c0, c2 = m * c1, c3 = m * c2, c4 = m * c3;
        v[0]  *= c0;
        v[1]  *= c1; v[2]  *= c1; v[4]  *= c1; v[8]  *= c1;
        v[3]  *= c2; v[5]  *= c2; v[6]  *= c2; v[9]  *= c2; v[10] *= c2; v[12] *= c2;
        v[7]  *= c3; v[11] *= c3; v[13] *= c3; v[14] *= c3;
        v[15] *= c4;
        #pragma unroll
        for (int s = 1; s < 16; s <<= 1)
            #pragma unroll
            for (int a = 0; a < 16; ++a)
                if ((a & s) == 0) {
                    const float u = v[a], t2 = v[a | s];
                    v[a] = u + t2; v[a | s] = u - t2;
                }
        float* lr = lut + i3 * 33 + lvl * 16;
        #pragma unroll
        for (int S = 0; S < 16; ++S) lr[S] = v[S];
    }
    __syncthreads();

    // ---- stage 4: 8 lanes share one i (broadcast pidx, near-conflict-free LDS) ----
    const int part = tid >> 3;                       // 0..31 i-partition
    const int bcol = tid & 7;                        // local batch
    const unsigned char* sb = sbT + bcol;
    float acc = 0.0f;
    #pragma unroll
    for (int j = 0; j < 4; ++j) {
        const int i = part * 4 + j;
        const uint32_t pk = pidx[i];
        const uint32_t cc0 = sb[(pk & 255u) * SSTR];
        const uint32_t cc1 = sb[((pk >> 8) & 255u) * SSTR];
        const uint32_t cc2 = sb[((pk >> 16) & 255u) * SSTR];
        const uint32_t cc3 = sb[(pk >> 24) * SSTR];
        const uint32_t S0 = (cc0 & 1u) | ((cc1 & 1u) << 1) | ((cc2 & 1u) << 2) | ((cc3 & 1u) << 3);
        const uint32_t S1 = (cc0 >> 1) | ((cc1 >> 1) << 1) | ((cc2 >> 1) << 2) | ((cc3 >> 1) << 3);
        const float* lr = lut + i * 33;              // odd stride: banks spread
        acc += lr[S0];
        acc += lr[16 + S1];
    }
    // parts live in lane bits 3..5: in-wave butterfly reduce (no LDS round-trip)
    acc += __shfl_xor(acc, 8);
    acc += __shfl_xor(acc, 16);
    acc += __shfl_xor(acc, 32);
    if ((tid & 63) < 8) wpart[tid >> 6][bcol] = acc;
    __syncthreads();

    // ---- stage 5: combine 4 wave partials, store ----
    if (tid < 8) {
        const float s = wpart[0][tid] + wpart[1][tid] + wpart[2][tid] + wpart[3][tid];
        out[(size_t)(b0 + tid) * OUT_ + o] = s + bo;
    }
}

extern "C" void kernel_launch(void* const* d_in, const int* in_sizes, int n_in,
                              void* d_out, int out_size, void* d_ws, size_t ws_size,
                              hipStream_t stream) {
    const float* x     = (const float*)d_in[0];
    const float* w     = (const float*)d_in[1];
    const float* bias  = (const float*)d_in[2];
    const float* means = (const float*)d_in[3];
    const int*   mask  = (const int*)d_in[4];
    float* out = (float*)d_out;
    hipLaunchKernelGGL(linlut_kernel, dim3(2048), dim3(256), 0, stream,
                       x, w, bias, means, mask, out);
}